// Round 10
// baseline (342.972 us; speedup 1.0000x reference)
//
#include <hip/hip_runtime.h>
#include <hip/hip_bf16.h>
#include <math.h>

#define NN 20000
#define NE 320000
#define DIM 512
#define LN_EPS 1e-5f
#define NEG_SLOPE 0.2f

typedef __attribute__((ext_vector_type(8))) short bf16x8;
typedef __attribute__((ext_vector_type(4))) float f32x4;
typedef __attribute__((ext_vector_type(4))) unsigned int u32x4;

__device__ inline void gload_lds16(const void* g, void* l) {
    __builtin_amdgcn_global_load_lds(
        (const __attribute__((address_space(1))) void*)g,
        (__attribute__((address_space(3))) void*)l, 16, 0, 0);
}

__device__ inline short f2bf(float f) {
    __hip_bfloat16 b = __float2bfloat16(f);
    return *reinterpret_cast<short*>(&b);
}

__device__ inline float bf2f(short u) {
    return __uint_as_float(((unsigned int)(unsigned short)u) << 16);
}

// ---------------- CSR build pieces (count is fused into gemm8's tail blocks) ----------------

__global__ __launch_bounds__(1024) void scan_k(const int* __restrict__ cnt,
                                               int* __restrict__ off,
                                               int* __restrict__ cur) {
    __shared__ int s[1024];
    const int t = threadIdx.x;
    const int lo = t * 20;
    int loc[20];
    int sum = 0;
#pragma unroll
    for (int i = 0; i < 20; i++) {
        int idx = lo + i;
        int v = (idx < NN) ? cnt[idx] : 0;
        loc[i] = v; sum += v;
    }
    s[t] = sum;
    __syncthreads();
    for (int o = 1; o < 1024; o <<= 1) {
        int x = (t >= o) ? s[t - o] : 0;
        __syncthreads();
        s[t] += x;
        __syncthreads();
    }
    int run = s[t] - sum;  // exclusive prefix
#pragma unroll
    for (int i = 0; i < 20; i++) {
        int idx = lo + i;
        if (idx < NN) { off[idx] = run; cur[idx] = run; run += loc[i]; }
    }
    if (t == 1023) off[NN] = s[1023];
}

__global__ void fill_k(const int* __restrict__ src, const int* __restrict__ dst,
                       int* __restrict__ cur, int* __restrict__ slot) {
    int e = blockIdx.x * blockDim.x + threadIdx.x;
    if (e < NE) {
        int d = dst[e];
        d = (d < 0) ? 0 : (d >= NN ? NN - 1 : d);
        int sv = src[e];
        sv = (sv < 0) ? 0 : (sv >= NN ? NN - 1 : sv);
        int p = atomicAdd(&cur[d], 1);
        slot[p] = sv;
    }
}

// ---------------- fused pre-pass: conv x->bf16 | zero cnt | transpose W1,W2 -> bf16 ----------------
#define NB_CONV 10000
#define NB_ZERO 20
__global__ __launch_bounds__(256) void convz_k(const float* __restrict__ in,
                                               __hip_bfloat16* __restrict__ out,
                                               int* __restrict__ cnt,
                                               const float* __restrict__ W1f,
                                               const float* __restrict__ W2f,
                                               __hip_bfloat16* __restrict__ B1,
                                               __hip_bfloat16* __restrict__ B2) {
    const int b = blockIdx.x;
    if (b < NB_CONV) {
        int i = (b * 256 + threadIdx.x) * 4;
        float4 v = *(const float4*)&in[i];
        out[i + 0] = __float2bfloat16(v.x);
        out[i + 1] = __float2bfloat16(v.y);
        out[i + 2] = __float2bfloat16(v.z);
        out[i + 3] = __float2bfloat16(v.w);
    } else if (b < NB_CONV + NB_ZERO) {
        int idx = (b - NB_CONV) * 256 + threadIdx.x;
        if (idx < NN / 4) ((int4*)cnt)[idx] = make_int4(0, 0, 0, 0);
    } else {
        // W[512][512] fp32 -> BT[n][k] bf16 (transpose); idx>>8 selects W1/W2
        const int idx = b - (NB_CONV + NB_ZERO);       // 0..511
        const int z = idx >> 8;
        const int rem = idx & 255;
        const int bk = (rem & 15) * 32, bn = (rem >> 4) * 32;
        const float* W = z ? W2f : W1f;
        __hip_bfloat16* BT = z ? B2 : B1;
        __shared__ float tile[32][33];
        const int tx = threadIdx.x & 31, ty = threadIdx.x >> 5;  // ty 0..7
#pragma unroll
        for (int i = 0; i < 32; i += 8)
            tile[ty + i][tx] = W[(size_t)(bk + ty + i) * DIM + bn + tx];
        __syncthreads();
#pragma unroll
        for (int i = 0; i < 32; i += 8)
            BT[(size_t)(bn + ty + i) * DIM + bk + tx] = __float2bfloat16(tile[tx][ty + i]);
    }
}

// ---------------- layer-1 GEMM: R9 structure unchanged (the A/B control) ----------------
// 128x128 tile, 4 waves, 16-step K-loop w/ per-step barriers; XCD swizzle; count_k tail.

template <int H>
__global__ __launch_bounds__(256) void gemm_mfma(const short* __restrict__ A,
                                                 const short* __restrict__ BT,
                                                 __hip_bfloat16* __restrict__ C,
                                                 const float* __restrict__ a_s,
                                                 const float* __restrict__ a_d,
                                                 float* __restrict__ p_as,
                                                 float* __restrict__ p_ad,
                                                 int M,
                                                 const int* __restrict__ e_dst,
                                                 int* __restrict__ cnt,
                                                 int gemmBlocks) {
    const int b = blockIdx.x;
    if (b >= gemmBlocks) {  // fused count_k tail (H=8 launch)
        int e = (b - gemmBlocks) * 256 + threadIdx.x;
        if (e < NE) {
            int d = e_dst[e];
            d = (d < 0) ? 0 : (d >= NN ? NN - 1 : d);
            atomicAdd(&cnt[d], 1);
        }
        return;
    }
    const int xq = gemmBlocks >> 3, xr = gemmBlocks & 7;
    const int xcd = b & 7, pos = b >> 3;
    const int L = (xcd < xr ? xcd * (xq + 1) : xr * (xq + 1) + (xcd - xr) * xq) + pos;
    const int bx = L & 3;
    const int by = L >> 2;

    __shared__ __align__(16) short SMEM[64 * 136];
    short* As = SMEM;
    short* Bs = SMEM + 4096;
    const int t = threadIdx.x;
    const int rowBase = by * 128;
    const int colBase = bx * 128;
    const int wave = t >> 6, lane = t & 63;
    const int wr = (wave >> 1) * 64;
    const int wc = (wave & 1) * 64;
    const int quad = lane >> 4, l16 = lane & 15;

    f32x4 acc[4][4];
#pragma unroll
    for (int i = 0; i < 4; i++)
#pragma unroll
        for (int j = 0; j < 4; j++) acc[i][j] = f32x4{0.f, 0.f, 0.f, 0.f};

    const int srow = t >> 2;
    const int skof = (t & 3) * 8;
    int ar0 = rowBase + srow;       if (ar0 > M - 1) ar0 = M - 1;
    int ar1 = rowBase + 64 + srow;  if (ar1 > M - 1) ar1 = M - 1;
    const int bn0 = colBase + srow;
    const int bn1 = colBase + 64 + srow;

    for (int k0 = 0; k0 < DIM; k0 += 32) {
        gload_lds16(A + (size_t)ar0 * DIM + k0 + skof, As + t * 8);
        gload_lds16(A + (size_t)ar1 * DIM + k0 + skof, As + 2048 + t * 8);
        gload_lds16(BT + (size_t)bn0 * DIM + k0 + skof, Bs + t * 8);
        gload_lds16(BT + (size_t)bn1 * DIM + k0 + skof, Bs + 2048 + t * 8);
        __syncthreads();

        bf16x8 af[4], bfr[4];
#pragma unroll
        for (int i = 0; i < 4; i++)
            af[i] = *(const bf16x8*)&As[(wr + i * 16 + l16) * 32 + quad * 8];
#pragma unroll
        for (int j = 0; j < 4; j++)
            bfr[j] = *(const bf16x8*)&Bs[(wc + j * 16 + l16) * 32 + quad * 8];
#pragma unroll
        for (int i = 0; i < 4; i++)
#pragma unroll
            for (int j = 0; j < 4; j++)
                acc[i][j] = __builtin_amdgcn_mfma_f32_16x16x32_bf16(af[i], bfr[j], acc[i][j], 0, 0, 0);
        __syncthreads();
    }

#pragma unroll
    for (int p = 0; p < 2; p++) {
        if ((wave >> 1) == p) {
#pragma unroll
            for (int i = 0; i < 4; i++)
#pragma unroll
                for (int j = 0; j < 4; j++)
#pragma unroll
                    for (int r = 0; r < 4; r++)
                        SMEM[(i * 16 + quad * 4 + r) * 136 + wc + j * 16 + l16] =
                            f2bf(acc[i][j][r]);
        }
        __syncthreads();
#pragma unroll
        for (int k = 0; k < 4; k++) {
            const int row = k * 16 + (t >> 4);
            const int col = (t & 15) * 8;
            const int gr = rowBase + p * 64 + row;
            if (gr < M) {
                bf16x8 vv = *(const bf16x8*)&SMEM[row * 136 + col];
                *(bf16x8*)&C[(size_t)gr * DIM + colBase + col] = vv;
            }
        }
        __syncthreads();
    }

    const int slab = 2 * bx + (wave & 1);
    const int cb = (H == 8) ? slab * 64 : (colBase + wc);
    float asc[4], adc[4];
#pragma unroll
    for (int j = 0; j < 4; j++) {
        asc[j] = a_s[cb + j * 16 + l16];
        adc[j] = a_d[cb + j * 16 + l16];
    }
#pragma unroll
    for (int i = 0; i < 4; i++) {
#pragma unroll
        for (int r = 0; r < 4; r++) {
            float vs = acc[i][0][r] * asc[0] + acc[i][1][r] * asc[1] +
                       acc[i][2][r] * asc[2] + acc[i][3][r] * asc[3];
            float vd = acc[i][0][r] * adc[0] + acc[i][1][r] * adc[1] +
                       acc[i][2][r] * adc[2] + acc[i][3][r] * adc[3];
#pragma unroll
            for (int o = 8; o; o >>= 1) { vs += __shfl_down(vs, o); vd += __shfl_down(vd, o); }
            if (l16 == 0) {
                const int row = rowBase + wr + i * 16 + quad * 4 + r;
                if (row < M) {
                    if (H == 8) {
                        p_as[(size_t)row * 8 + slab] = vs;
                        p_ad[(size_t)row * 8 + slab] = vd;
                    } else {
                        atomicAdd(&p_as[row], vs);
                        atomicAdd(&p_ad[row], vd);
                    }
                }
            }
        }
    }
}

// ---------------- layer-2 GEMM: WEIGHT-STATIONARY, BARRIER-FREE (the A/B experiment) ----------------
// W2 is 512KB; a 128-col slab of BT2 (128x512 bf16 = 128KB) is LDS-RESIDENT for the whole
// block. ONE barrier after the slab load; then the M/K loop has ZERO barriers: A-fragments
// load per-lane DIRECTLY from global (16 rows x 64B coalesced per quad-window), B-fragments
// ds_read from the resident slab. The compiler can pipeline loads across k-steps (nothing
// blocks code motion), so the 16-step stage->drain->compute serial path of the old kernel
// disappears. C stored direct (32B segments). Grid 512 = 4 col-slabs x 128 row-groups,
// XCD-remapped so one row-group's 4 slab-sharers sit on one XCD (A HBM ~1x).
// LDS swizzle (rule #21): gload_lds dest linear; global SOURCE k pre-XORed by (c&7)*8;
// ds_read XORs the same -> stride-1-equivalent bank pattern.
// Alpha: wave's 64-col partial dot -> atomicAdd into flat p_as/p_ad (zeroed by agg8).

__global__ __launch_bounds__(256) void gemm_ws1(const short* __restrict__ A,
                                                const short* __restrict__ BT,
                                                __hip_bfloat16* __restrict__ C,
                                                const float* __restrict__ a_s,
                                                const float* __restrict__ a_d,
                                                float* __restrict__ p_as,
                                                float* __restrict__ p_ad,
                                                int M) {
    __shared__ __align__(16) short Bs[128 * 512];   // 128 KB, resident all-kernel
    const int t = threadIdx.x;
    const int b = blockIdx.x;
    // XCD remap: xcd = b&7 owns logical L in a contiguous run of 64 -> same-row-group
    // slab-sharers (L = 4q..4q+3) colocate on one XCD.
    const int L = (b & 7) * 64 + (b >> 3);
    const int slabIdx = L & 3;
    const int q = L >> 2;                  // row-group 0..127
    const int colBase = slabIdx * 128;
    const int wave = t >> 6, lane = t & 63;
    const int wr = (wave >> 1) * 64;
    const int wc = (wave & 1) * 64;
    const int quad = lane >> 4, l16 = lane & 15;

    // ---- load W-slab once: 8192 slots of 16B; slot s -> col c = s>>6, k8 = (s&63)*8.
    // source k pre-swizzled: k_src = k8 ^ ((c&7)*8); LDS dest linear (Bs + s*8 shorts).
#pragma unroll
    for (int i = 0; i < 32; i++) {
        const int s = t + 256 * i;
        const int c = s >> 6;
        const int k8 = (s & 63) * 8;
        const int ksrc = k8 ^ ((c & 7) * 8);
        gload_lds16(BT + (size_t)(colBase + c) * DIM + ksrc, Bs + (size_t)s * 8);
    }
    __syncthreads();   // the ONLY barrier

    const int swz = (l16 & 7) * 8;         // read-side XOR (uniform over j since wc,j*16 are mult of 8)

    // ---- M loop: row-groups g = q and q+128 (if <157), 128 rows each
    const int ng = (q + 128 < (M + 127) / 128) ? 2 : 1;
    for (int gi = 0; gi < ng; gi++) {
        const int g = (gi == 0) ? q : q + 128;
        const int rowBase = g * 128;

        f32x4 acc[4][4];
#pragma unroll
        for (int i = 0; i < 4; i++)
#pragma unroll
            for (int j = 0; j < 4; j++) acc[i][j] = f32x4{0.f, 0.f, 0.f, 0.f};

        // per-lane A rows (clamped at tail)
        int arow[4];
#pragma unroll
        for (int i = 0; i < 4; i++) {
            int r = rowBase + wr + i * 16 + l16;
            arow[i] = (r > M - 1) ? (M - 1) : r;
        }

#pragma unroll 4
        for (int k0 = 0; k0 < DIM; k0 += 32) {
            bf16x8 af[4], bfr[4];
#pragma unroll
            for (int i = 0; i < 4; i++)
                af[i] = *(const bf16x8*)&A[(size_t)arow[i] * DIM + k0 + quad * 8];
#pragma unroll
            for (int j = 0; j < 4; j++)
                bfr[j] = *(const bf16x8*)&Bs[(wc + j * 16 + l16) * 512 + ((k0 + quad * 8) ^ swz)];
#pragma unroll
            for (int i = 0; i < 4; i++)
#pragma unroll
                for (int j = 0; j < 4; j++)
                    acc[i][j] = __builtin_amdgcn_mfma_f32_16x16x32_bf16(af[i], bfr[j], acc[i][j], 0, 0, 0);
        }

        // ---- C direct store: per (i,j,r) 16 lanes x 2B = 32B segments
#pragma unroll
        for (int i = 0; i < 4; i++) {
#pragma unroll
            for (int r = 0; r < 4; r++) {
                const int row = rowBase + wr + i * 16 + quad * 4 + r;
                if (row < M) {
#pragma unroll
                    for (int j = 0; j < 4; j++)
                        *(short*)&C[(size_t)row * DIM + colBase + wc + j * 16 + l16] =
                            f2bf(acc[i][j][r]);
                }
            }
        }

        // ---- alpha: wave's 64-col partial dot -> atomic into flat [NN]
        float asc[4], adc[4];
#pragma unroll
        for (int j = 0; j < 4; j++) {
            asc[j] = a_s[colBase + wc + j * 16 + l16];
            adc[j] = a_d[colBase + wc + j * 16 + l16];
        }
#pragma unroll
        for (int i = 0; i < 4; i++) {
#pragma unroll
            for (int r = 0; r < 4; r++) {
                float vs = acc[i][0][r] * asc[0] + acc[i][1][r] * asc[1] +
                           acc[i][2][r] * asc[2] + acc[i][3][r] * asc[3];
                float vd = acc[i][0][r] * adc[0] + acc[i][1][r] * adc[1] +
                           acc[i][2][r] * adc[2] + acc[i][3][r] * adc[3];
#pragma unroll
                for (int o = 8; o; o >>= 1) { vs += __shfl_down(vs, o); vd += __shfl_down(vd, o); }
                if (l16 == 0) {
                    const int row = rowBase + wr + i * 16 + quad * 4 + r;
                    if (row < M) {
                        atomicAdd(&p_as[row], vs);
                        atomicAdd(&p_ad[row], vd);
                    }
                }
            }
        }
    }
}

// ---------------- fused aggregation: ONE WAVE PER NODE (h in bf16) ----------------
// Main loop = EXACT R0 structure (6 rounds reproduced at its L2-miss-traffic floor).
// DO NOT TOUCH the edge loop.

template <int H>
__global__ __launch_bounds__(256) void agg_k(const __hip_bfloat16* __restrict__ h,
                                             const float* __restrict__ alp_s,
                                             const float* __restrict__ alp_d,
                                             const int* __restrict__ off,
                                             const int* __restrict__ slot,
                                             const float* __restrict__ bias,
                                             const float* __restrict__ gamma,
                                             const float* __restrict__ beta,
                                             const __hip_bfloat16* x_resb,
                                             float* x_out,
                                             __hip_bfloat16* x_out_b,
                                             float* __restrict__ zs,
                                             float* __restrict__ zd) {
    if (H == 8 && threadIdx.x < 4) {   // zero next layer's alpha accumulators
        const int zi = blockIdx.x * 4 + threadIdx.x;
        if (zi < NN) { zs[zi] = 0.f; zd[zi] = 0.f; }
    }
    const int wid = threadIdx.x >> 6;
    const int lane = threadIdx.x & 63;
    const int n = blockIdx.x * 4 + wid;
    const int head = (H == 8) ? (lane >> 3) : 0;

    const int o0 = off[n];
    const int deg = off[n + 1] - o0;
    const int total = deg + 1;  // + self loop

    const float ad = (H == 8) ? alp_d[(size_t)n * 8 + head] : alp_d[n];

    int v = 0x7fffffff;
    if (lane < total && lane < 64) v = (lane < deg) ? slot[o0 + lane] : n;
#pragma unroll
    for (int k = 2; k <= 64; k <<= 1) {
#pragma unroll
        for (int j = k >> 1; j > 0; j >>= 1) {
            int o = __shfl_xor(v, j);
            bool takeMin = (((lane & k) == 0) == ((lane & j) == 0));
            v = takeMin ? min(v, o) : max(v, o);
        }
    }
    const int nsort = (total < 64) ? total : 64;

    float acc[8];
#pragma unroll
    for (int r = 0; r < 8; r++) acc[r] = 0.f;
    float ld = 0.f;
    const unsigned short* hu = (const unsigned short*)h;

    auto zcomp = [&](int s) -> float {
        float z = ((H == 8) ? alp_s[(size_t)s * 8 + head] : alp_s[s]) + ad;
        return (z >= 0.f) ? z : NEG_SLOPE * z;
    };
    auto fmarow = [&](const u32x4& rv, float p) {
#pragma unroll
        for (int q = 0; q < 4; q++) {
            unsigned int u = rv[q];
            acc[2 * q]     += p * __uint_as_float(u << 16);
            acc[2 * q + 1] += p * __uint_as_float(u & 0xffff0000u);
        }
    };

    int e = 0;
    for (; e + 4 <= nsort; e += 4) {
        const int s0 = __shfl(v, e), s1 = __shfl(v, e + 1);
        const int s2 = __shfl(v, e + 2), s3 = __shfl(v, e + 3);
        const u32x4 r0 = *(const u32x4*)(hu + (size_t)s0 * DIM + lane * 8);
        const u32x4 r1 = *(const u32x4*)(hu + (size_t)s1 * DIM + lane * 8);
        const u32x4 r2 = *(const u32x4*)(hu + (size_t)s2 * DIM + lane * 8);
        const u32x4 r3 = *(const u32x4*)(hu + (size_t)s3 * DIM + lane * 8);
        const float z0 = zcomp(s0), z1 = zcomp(s1), z2 = zcomp(s2), z3 = zcomp(s3);
        const float p0 = __expf(z0), p1 = __expf(z1), p2 = __expf(z2), p3 = __expf(z3);
        ld += p0; fmarow(r0, p0);
        ld += p1; fmarow(r1, p1);
        ld += p2; fmarow(r2, p2);
        ld += p3; fmarow(r3, p3);
    }
    for (; e < nsort; e++) {
        const int s = __shfl(v, e);
        const u32x4 rv = *(const u32x4*)(hu + (size_t)s * DIM + lane * 8);
        const float p = __expf(zcomp(s));
        ld += p; fmarow(rv, p);
    }
    for (int e2 = 64; e2 < total; e2++) {
        const int s = (e2 < deg) ? slot[o0 + e2] : n;
        const u32x4 rv = *(const u32x4*)(hu + (size_t)s * DIM + lane * 8);
        const float p = __expf(zcomp(s));
        ld += p; fmarow(rv, p);
    }

    const float inv = 1.f / ld;
    const int c0 = lane * 8;
    const float4 ba = *(const float4*)&bias[c0];
    const float4 bb = *(const float4*)&bias[c0 + 4];
    float xn[8];
    xn[0] = acc[0] * inv + ba.x; xn[1] = acc[1] * inv + ba.y;
    xn[2] = acc[2] * inv + ba.z; xn[3] = acc[3] * inv + ba.w;
    xn[4] = acc[4] * inv + bb.x; xn[5] = acc[5] * inv + bb.y;
    xn[6] = acc[6] * inv + bb.z; xn[7] = acc[7] * inv + bb.w;

    float s1 = 0.f, s2 = 0.f;
#pragma unroll
    for (int r = 0; r < 8; r++) { s1 += xn[r]; s2 += xn[r] * xn[r]; }
#pragma unroll
    for (int o = 32; o; o >>= 1) { s1 += __shfl_xor(s1, o); s2 += __shfl_xor(s2, o); }
    const float mu = s1 * (1.f / DIM);
    const float rs = rsqrtf(s2 * (1.f / DIM) - mu * mu + LN_EPS);

    const float4 ga = *(const float4*)&gamma[c0];
    const float4 gb = *(const float4*)&gamma[c0 + 4];
    const float4 ea = *(const float4*)&beta[c0];
    const float4 eb = *(const float4*)&beta[c0 + 4];
    const bf16x8 xrv = *(const bf16x8*)&x_resb[(size_t)n * DIM + c0];
    const float gv[8] = {ga.x, ga.y, ga.z, ga.w, gb.x, gb.y, gb.z, gb.w};
    const float ev[8] = {ea.x, ea.y, ea.z, ea.w, eb.x, eb.y, eb.z, eb.w};

    float out[8];
#pragma unroll
    for (int r = 0; r < 8; r++) {
        float y = (xn[r] - mu) * rs * gv[r] + ev[r];
        y = (y > 0.f) ? y : expm1f(y);
        out[r] = bf2f(xrv[r]) + y;
    }
    if (x_out) {
        *(float4*)&x_out[(size_t)n * DIM + c0]     = make_float4(out[0], out[1], out[2], out[3]);
        *(float4*)&x_out[(size_t)n * DIM + c0 + 4] = make_float4(out[4], out[5], out[6], out[7]);
    }
    if (x_out_b) {
        __hip_bfloat16 tb[8];
#pragma unroll
        for (int r = 0; r < 8; r++) tb[r] = __float2bfloat16(out[r]);
        *(bf16x8*)&x_out_b[(size_t)n * DIM + c0] = *(bf16x8*)tb;
    }
}

// ---------------- launch (7 dispatches) ----------------

extern "C" void kernel_launch(void* const* d_in, const int* in_sizes, int n_in,
                              void* d_out, int out_size, void* d_ws, size_t ws_size,
                              hipStream_t stream) {
    const float* x = (const float*)d_in[0];
    const int* ei = (const int*)d_in[1];
    const float* W1 = (const float*)d_in[2];
    const float* as1 = (const float*)d_in[3];
    const float* ad1 = (const float*)d_in[4];
    const float* b1 = (const float*)d_in[5];
    const float* g1 = (const float*)d_in[6];
    const float* be1 = (const float*)d_in[7];
    const float* W2 = (const float*)d_in[8];
    const float* as2 = (const float*)d_in[9];
    const float* ad2 = (const float*)d_in[10];
    const float* b2 = (const float*)d_in[11];
    const float* g2 = (const float*)d_in[12];
    const float* be2 = (const float*)d_in[13];
    float* out = (float*)d_out;

    char* ws = (char*)d_ws;
    size_t o = 0;
    auto alloc = [&](size_t bytes) { size_t r = o; o += (bytes + 255) & ~(size_t)255; return r; };
    int* p_cnt = (int*)(ws + alloc((size_t)NN * 4));
    int* p_off = (int*)(ws + alloc((size_t)(NN + 1) * 4));
    int* p_cur = (int*)(ws + alloc((size_t)NN * 4));
    int* p_slot = (int*)(ws + alloc((size_t)NE * 4));
    __hip_bfloat16* p_hb = (__hip_bfloat16*)(ws + alloc((size_t)NN * DIM * 2));
    __hip_bfloat16* p_xb = (__hip_bfloat16*)(ws + alloc((size_t)NN * DIM * 2));
    __hip_bfloat16* p_bt1 = (__hip_bfloat16*)(ws + alloc((size_t)DIM * DIM * 2));
    __hip_bfloat16* p_bt2 = (__hip_bfloat16*)(ws + alloc((size_t)DIM * DIM * 2));
    float* p_as = (float*)(ws + alloc((size_t)NN * 8 * 4));
    float* p_ad = (float*)(ws + alloc((size_t)NN * 8 * 4));
    float* p_as2 = (float*)(ws + alloc((size_t)NN * 4));
    float* p_ad2 = (float*)(ws + alloc((size_t)NN * 4));

    const int* e_src = ei;
    const int* e_dst = ei + NE;

    const int GB = 4 * ((NN + 127) / 128);   // 628 gemm8 blocks
    const int CB = (NE + 255) / 256;         // 1250 count/fill blocks

    // 1: conv x->bf16 + zero cnt + transpose W1,W2
    convz_k<<<NB_CONV + NB_ZERO + 512, 256, 0, stream>>>(x, p_xb, p_cnt, W1, W2, p_bt1, p_bt2);
    // 2: layer-1 GEMM (R9 control) + fused edge-count tail
    gemm_mfma<8><<<GB + CB, 256, 0, stream>>>((const short*)p_xb, (const short*)p_bt1, p_hb,
                                              as1, ad1, p_as, p_ad, NN, e_dst, p_cnt, GB);
    // 3-4: CSR offsets + fill
    scan_k<<<1, 1024, 0, stream>>>(p_cnt, p_off, p_cur);
    fill_k<<<CB, 256, 0, stream>>>(e_src, e_dst, p_cur, p_slot);
    // 5: layer-1 aggregation (+ zero p_as2/p_ad2 for gemm_ws1's atomic epilogue)
    agg_k<8><<<NN / 4, 256, 0, stream>>>(p_hb, p_as, p_ad, p_off, p_slot, b1, g1, be1,
                                         p_xb, nullptr, p_xb, p_as2, p_ad2);
    // 6: layer-2 GEMM -- weight-stationary barrier-free (the A/B experiment)
    gemm_ws1<<<512, 256, 0, stream>>>((const short*)p_xb, (const short*)p_bt2, p_hb,
                                      as2, ad2, p_as2, p_ad2, NN);
    // 7: layer-2 aggregation -> final fp32 out
    agg_k<1><<<NN / 4, 256, 0, stream>>>(p_hb, p_as2, p_ad2, p_off, p_slot, b2, g2, be2,
                                         p_xb, out, nullptr, nullptr, nullptr);
}

// Round 11
// 288.011 us; speedup vs baseline: 1.1908x; 1.1908x over previous
//
#include <hip/hip_runtime.h>
#include <hip/hip_bf16.h>
#include <math.h>

#define NN 20000
#define NE 320000
#define DIM 512
#define LN_EPS 1e-5f
#define NEG_SLOPE 0.2f

typedef __attribute__((ext_vector_type(8))) short bf16x8;
typedef __attribute__((ext_vector_type(4))) float f32x4;
typedef __attribute__((ext_vector_type(4))) unsigned int u32x4;

__device__ inline void gload_lds16(const void* g, void* l) {
    __builtin_amdgcn_global_load_lds(
        (const __attribute__((address_space(1))) void*)g,
        (__attribute__((address_space(3))) void*)l, 16, 0, 0);
}

__device__ inline short f2bf(float f) {
    __hip_bfloat16 b = __float2bfloat16(f);
    return *reinterpret_cast<short*>(&b);
}

__device__ inline float bf2f(short u) {
    return __uint_as_float(((unsigned int)(unsigned short)u) << 16);
}

// ---------------- CSR build ----------------
// count is fused into gemm8's tail blocks. Offsets via PARALLEL ATOMIC ALLOCATION (R11):
// off[] need not be monotonic -- any disjoint partition works, since agg takes deg from
// cnt[n] (not off[n+1]-off[n]) and sorts each src list in-register before accumulating.
// Explicit wave prefix-sum + ONE atomicAdd per wave (313 total) replaces the serial
// single-block scan (~10-15 us -> ~2 us).

__global__ void alloc_k(const int* __restrict__ cnt, int* __restrict__ off,
                        int* __restrict__ cur, int* __restrict__ gtot) {
    const int n = blockIdx.x * blockDim.x + threadIdx.x;
    const int lane = threadIdx.x & 63;
    int c = (n < NN) ? cnt[n] : 0;
    int pre = c;  // inclusive wave scan
#pragma unroll
    for (int o = 1; o < 64; o <<= 1) {
        int t = __shfl_up(pre, o);
        if (lane >= o) pre += t;
    }
    int wtot = __shfl(pre, 63);
    int base = 0;
    if (lane == 63) base = atomicAdd(gtot, wtot);
    base = __shfl(base, 63);
    if (n < NN) {
        int o0 = base + pre - c;  // exclusive within wave
        off[n] = o0;
        cur[n] = o0;
    }
}

__global__ void fill_k(const int* __restrict__ src, const int* __restrict__ dst,
                       int* __restrict__ cur, int* __restrict__ slot) {
    int e = blockIdx.x * blockDim.x + threadIdx.x;
    if (e < NE) {
        int d = dst[e];
        d = (d < 0) ? 0 : (d >= NN ? NN - 1 : d);
        int sv = src[e];
        sv = (sv < 0) ? 0 : (sv >= NN ? NN - 1 : sv);
        int p = atomicAdd(&cur[d], 1);
        slot[p] = sv;
    }
}

// ---------------- fused pre-pass: conv x->bf16 | zero cnt+gtot | transpose W1,W2 ----------------
#define NB_CONV 10000
#define NB_ZERO 20
__global__ __launch_bounds__(256) void convz_k(const float* __restrict__ in,
                                               __hip_bfloat16* __restrict__ out,
                                               int* __restrict__ cnt,
                                               const float* __restrict__ W1f,
                                               const float* __restrict__ W2f,
                                               __hip_bfloat16* __restrict__ B1,
                                               __hip_bfloat16* __restrict__ B2,
                                               int* __restrict__ gtot) {
    const int b = blockIdx.x;
    if (b < NB_CONV) {
        int i = (b * 256 + threadIdx.x) * 4;
        float4 v = *(const float4*)&in[i];
        out[i + 0] = __float2bfloat16(v.x);
        out[i + 1] = __float2bfloat16(v.y);
        out[i + 2] = __float2bfloat16(v.z);
        out[i + 3] = __float2bfloat16(v.w);
    } else if (b < NB_CONV + NB_ZERO) {
        int idx = (b - NB_CONV) * 256 + threadIdx.x;
        if (idx < NN / 4) ((int4*)cnt)[idx] = make_int4(0, 0, 0, 0);
        if (idx == 0) *gtot = 0;
    } else {
        // W[512][512] fp32 -> BT[n][k] bf16 (transpose); idx>>8 selects W1/W2
        const int idx = b - (NB_CONV + NB_ZERO);       // 0..511
        const int z = idx >> 8;
        const int rem = idx & 255;
        const int bk = (rem & 15) * 32, bn = (rem >> 4) * 32;
        const float* W = z ? W2f : W1f;
        __hip_bfloat16* BT = z ? B2 : B1;
        __shared__ float tile[32][33];
        const int tx = threadIdx.x & 31, ty = threadIdx.x >> 5;  // ty 0..7
#pragma unroll
        for (int i = 0; i < 32; i += 8)
            tile[ty + i][tx] = W[(size_t)(bk + ty + i) * DIM + bn + tx];
        __syncthreads();
#pragma unroll
        for (int i = 0; i < 32; i += 8)
            BT[(size_t)(bn + ty + i) * DIM + bk + tx] = __float2bfloat16(tile[tx][ty + i]);
    }
}

// ---------------- bf16 MFMA GEMM + fused alpha epilogue (R9-verified structure) ----------------
// 128x128 tile, 4 waves, 16-step K-loop w/ per-step barriers (measured local optimum:
// dbuf neutral R2, BK=64+swz -13us R6, 64x128 -40us R5, weight-stationary -34us R10).
// ~30 us each (~350 TF, latency-bound; FETCH shows L3 absorbs A re-reads). XCD swizzle
// kept (null but harmless). H=8: +count_k tail blocks. H=1: alpha -> flat atomics.

template <int H>
__global__ __launch_bounds__(256) void gemm_mfma(const short* __restrict__ A,
                                                 const short* __restrict__ BT,
                                                 __hip_bfloat16* __restrict__ C,
                                                 const float* __restrict__ a_s,
                                                 const float* __restrict__ a_d,
                                                 float* __restrict__ p_as,
                                                 float* __restrict__ p_ad,
                                                 int M,
                                                 const int* __restrict__ e_dst,
                                                 int* __restrict__ cnt,
                                                 int gemmBlocks) {
    const int b = blockIdx.x;
    if (b >= gemmBlocks) {  // fused count_k tail (H=8 launch)
        int e = (b - gemmBlocks) * 256 + threadIdx.x;
        if (e < NE) {
            int d = e_dst[e];
            d = (d < 0) ? 0 : (d >= NN ? NN - 1 : d);
            atomicAdd(&cnt[d], 1);
        }
        return;
    }
    const int xq = gemmBlocks >> 3, xr = gemmBlocks & 7;
    const int xcd = b & 7, pos = b >> 3;
    const int L = (xcd < xr ? xcd * (xq + 1) : xr * (xq + 1) + (xcd - xr) * xq) + pos;
    const int bx = L & 3;
    const int by = L >> 2;

    __shared__ __align__(16) short SMEM[64 * 136];
    short* As = SMEM;
    short* Bs = SMEM + 4096;
    const int t = threadIdx.x;
    const int rowBase = by * 128;
    const int colBase = bx * 128;
    const int wave = t >> 6, lane = t & 63;
    const int wr = (wave >> 1) * 64;
    const int wc = (wave & 1) * 64;
    const int quad = lane >> 4, l16 = lane & 15;

    f32x4 acc[4][4];
#pragma unroll
    for (int i = 0; i < 4; i++)
#pragma unroll
        for (int j = 0; j < 4; j++) acc[i][j] = f32x4{0.f, 0.f, 0.f, 0.f};

    const int srow = t >> 2;
    const int skof = (t & 3) * 8;
    int ar0 = rowBase + srow;       if (ar0 > M - 1) ar0 = M - 1;
    int ar1 = rowBase + 64 + srow;  if (ar1 > M - 1) ar1 = M - 1;
    const int bn0 = colBase + srow;
    const int bn1 = colBase + 64 + srow;

    for (int k0 = 0; k0 < DIM; k0 += 32) {
        gload_lds16(A + (size_t)ar0 * DIM + k0 + skof, As + t * 8);
        gload_lds16(A + (size_t)ar1 * DIM + k0 + skof, As + 2048 + t * 8);
        gload_lds16(BT + (size_t)bn0 * DIM + k0 + skof, Bs + t * 8);
        gload_lds16(BT + (size_t)bn1 * DIM + k0 + skof, Bs + 2048 + t * 8);
        __syncthreads();

        bf16x8 af[4], bfr[4];
#pragma unroll
        for (int i = 0; i < 4; i++)
            af[i] = *(const bf16x8*)&As[(wr + i * 16 + l16) * 32 + quad * 8];
#pragma unroll
        for (int j = 0; j < 4; j++)
            bfr[j] = *(const bf16x8*)&Bs[(wc + j * 16 + l16) * 32 + quad * 8];
#pragma unroll
        for (int i = 0; i < 4; i++)
#pragma unroll
            for (int j = 0; j < 4; j++)
                acc[i][j] = __builtin_amdgcn_mfma_f32_16x16x32_bf16(af[i], bfr[j], acc[i][j], 0, 0, 0);
        __syncthreads();
    }

#pragma unroll
    for (int p = 0; p < 2; p++) {
        if ((wave >> 1) == p) {
#pragma unroll
            for (int i = 0; i < 4; i++)
#pragma unroll
                for (int j = 0; j < 4; j++)
#pragma unroll
                    for (int r = 0; r < 4; r++)
                        SMEM[(i * 16 + quad * 4 + r) * 136 + wc + j * 16 + l16] =
                            f2bf(acc[i][j][r]);
        }
        __syncthreads();
#pragma unroll
        for (int k = 0; k < 4; k++) {
            const int row = k * 16 + (t >> 4);
            const int col = (t & 15) * 8;
            const int gr = rowBase + p * 64 + row;
            if (gr < M) {
                bf16x8 vv = *(const bf16x8*)&SMEM[row * 136 + col];
                *(bf16x8*)&C[(size_t)gr * DIM + colBase + col] = vv;
            }
        }
        __syncthreads();
    }

    const int slab = 2 * bx + (wave & 1);
    const int cb = (H == 8) ? slab * 64 : (colBase + wc);
    float asc[4], adc[4];
#pragma unroll
    for (int j = 0; j < 4; j++) {
        asc[j] = a_s[cb + j * 16 + l16];
        adc[j] = a_d[cb + j * 16 + l16];
    }
#pragma unroll
    for (int i = 0; i < 4; i++) {
#pragma unroll
        for (int r = 0; r < 4; r++) {
            float vs = acc[i][0][r] * asc[0] + acc[i][1][r] * asc[1] +
                       acc[i][2][r] * asc[2] + acc[i][3][r] * asc[3];
            float vd = acc[i][0][r] * adc[0] + acc[i][1][r] * adc[1] +
                       acc[i][2][r] * adc[2] + acc[i][3][r] * adc[3];
#pragma unroll
            for (int o = 8; o; o >>= 1) { vs += __shfl_down(vs, o); vd += __shfl_down(vd, o); }
            if (l16 == 0) {
                const int row = rowBase + wr + i * 16 + quad * 4 + r;
                if (row < M) {
                    if (H == 8) {
                        p_as[(size_t)row * 8 + slab] = vs;
                        p_ad[(size_t)row * 8 + slab] = vd;
                    } else {
                        atomicAdd(&p_as[row], vs);
                        atomicAdd(&p_ad[row], vd);
                    }
                }
            }
        }
    }
}

// ---------------- fused aggregation: ONE WAVE PER NODE (h in bf16) ----------------
// Main loop = EXACT R0 structure (6 rounds at its L2-miss/fabric floor: FETCH = 8 XCD x
// h-size = 162 MB at ~3.5-4 TB/s). DO NOT TOUCH the edge loop.
// deg now comes from cnt[n] (off[] is an arbitrary-order partition from alloc_k; the
// in-register bitonic sort makes accumulation order independent of slot layout).

template <int H>
__global__ __launch_bounds__(256) void agg_k(const __hip_bfloat16* __restrict__ h,
                                             const float* __restrict__ alp_s,
                                             const float* __restrict__ alp_d,
                                             const int* __restrict__ off,
                                             const int* __restrict__ degc,
                                             const int* __restrict__ slot,
                                             const float* __restrict__ bias,
                                             const float* __restrict__ gamma,
                                             const float* __restrict__ beta,
                                             const __hip_bfloat16* x_resb,
                                             float* x_out,
                                             __hip_bfloat16* x_out_b,
                                             float* __restrict__ zs,
                                             float* __restrict__ zd) {
    if (H == 8 && threadIdx.x < 4) {   // zero next layer's alpha accumulators
        const int zi = blockIdx.x * 4 + threadIdx.x;
        if (zi < NN) { zs[zi] = 0.f; zd[zi] = 0.f; }
    }
    const int wid = threadIdx.x >> 6;
    const int lane = threadIdx.x & 63;
    const int n = blockIdx.x * 4 + wid;
    const int head = (H == 8) ? (lane >> 3) : 0;

    const int o0 = off[n];
    const int deg = degc[n];
    const int total = deg + 1;  // + self loop

    const float ad = (H == 8) ? alp_d[(size_t)n * 8 + head] : alp_d[n];

    int v = 0x7fffffff;
    if (lane < total && lane < 64) v = (lane < deg) ? slot[o0 + lane] : n;
#pragma unroll
    for (int k = 2; k <= 64; k <<= 1) {
#pragma unroll
        for (int j = k >> 1; j > 0; j >>= 1) {
            int o = __shfl_xor(v, j);
            bool takeMin = (((lane & k) == 0) == ((lane & j) == 0));
            v = takeMin ? min(v, o) : max(v, o);
        }
    }
    const int nsort = (total < 64) ? total : 64;

    float acc[8];
#pragma unroll
    for (int r = 0; r < 8; r++) acc[r] = 0.f;
    float ld = 0.f;
    const unsigned short* hu = (const unsigned short*)h;

    auto zcomp = [&](int s) -> float {
        float z = ((H == 8) ? alp_s[(size_t)s * 8 + head] : alp_s[s]) + ad;
        return (z >= 0.f) ? z : NEG_SLOPE * z;
    };
    auto fmarow = [&](const u32x4& rv, float p) {
#pragma unroll
        for (int q = 0; q < 4; q++) {
            unsigned int u = rv[q];
            acc[2 * q]     += p * __uint_as_float(u << 16);
            acc[2 * q + 1] += p * __uint_as_float(u & 0xffff0000u);
        }
    };

    int e = 0;
    for (; e + 4 <= nsort; e += 4) {
        const int s0 = __shfl(v, e), s1 = __shfl(v, e + 1);
        const int s2 = __shfl(v, e + 2), s3 = __shfl(v, e + 3);
        const u32x4 r0 = *(const u32x4*)(hu + (size_t)s0 * DIM + lane * 8);
        const u32x4 r1 = *(const u32x4*)(hu + (size_t)s1 * DIM + lane * 8);
        const u32x4 r2 = *(const u32x4*)(hu + (size_t)s2 * DIM + lane * 8);
        const u32x4 r3 = *(const u32x4*)(hu + (size_t)s3 * DIM + lane * 8);
        const float z0 = zcomp(s0), z1 = zcomp(s1), z2 = zcomp(s2), z3 = zcomp(s3);
        const float p0 = __expf(z0), p1 = __expf(z1), p2 = __expf(z2), p3 = __expf(z3);
        ld += p0; fmarow(r0, p0);
        ld += p1; fmarow(r1, p1);
        ld += p2; fmarow(r2, p2);
        ld += p3; fmarow(r3, p3);
    }
    for (; e < nsort; e++) {
        const int s = __shfl(v, e);
        const u32x4 rv = *(const u32x4*)(hu + (size_t)s * DIM + lane * 8);
        const float p = __expf(zcomp(s));
        ld += p; fmarow(rv, p);
    }
    for (int e2 = 64; e2 < total; e2++) {
        const int s = (e2 < deg) ? slot[o0 + e2] : n;
        const u32x4 rv = *(const u32x4*)(hu + (size_t)s * DIM + lane * 8);
        const float p = __expf(zcomp(s));
        ld += p; fmarow(rv, p);
    }

    const float inv = 1.f / ld;
    const int c0 = lane * 8;
    const float4 ba = *(const float4*)&bias[c0];
    const float4 bb = *(const float4*)&bias[c0 + 4];
    float xn[8];
    xn[0] = acc[0] * inv + ba.x; xn[1] = acc[1] * inv + ba.y;
    xn[2] = acc[2] * inv + ba.z; xn[3] = acc[3] * inv + ba.w;
    xn[4] = acc[4] * inv + bb.x; xn[5] = acc[5] * inv + bb.y;
    xn[6] = acc[6] * inv + bb.z; xn[7] = acc[7] * inv + bb.w;

    float s1 = 0.f, s2 = 0.f;
#pragma unroll
    for (int r = 0; r < 8; r++) { s1 += xn[r]; s2 += xn[r] * xn[r]; }
#pragma unroll
    for (int o = 32; o; o >>= 1) { s1 += __shfl_xor(s1, o); s2 += __shfl_xor(s2, o); }
    const float mu = s1 * (1.f / DIM);
    const float rs = rsqrtf(s2 * (1.f / DIM) - mu * mu + LN_EPS);

    const float4 ga = *(const float4*)&gamma[c0];
    const float4 gb = *(const float4*)&gamma[c0 + 4];
    const float4 ea = *(const float4*)&beta[c0];
    const float4 eb = *(const float4*)&beta[c0 + 4];
    const bf16x8 xrv = *(const bf16x8*)&x_resb[(size_t)n * DIM + c0];
    const float gv[8] = {ga.x, ga.y, ga.z, ga.w, gb.x, gb.y, gb.z, gb.w};
    const float ev[8] = {ea.x, ea.y, ea.z, ea.w, eb.x, eb.y, eb.z, eb.w};

    float out[8];
#pragma unroll
    for (int r = 0; r < 8; r++) {
        float y = (xn[r] - mu) * rs * gv[r] + ev[r];
        y = (y > 0.f) ? y : expm1f(y);
        out[r] = bf2f(xrv[r]) + y;
    }
    if (x_out) {
        *(float4*)&x_out[(size_t)n * DIM + c0]     = make_float4(out[0], out[1], out[2], out[3]);
        *(float4*)&x_out[(size_t)n * DIM + c0 + 4] = make_float4(out[4], out[5], out[6], out[7]);
    }
    if (x_out_b) {
        __hip_bfloat16 tb[8];
#pragma unroll
        for (int r = 0; r < 8; r++) tb[r] = __float2bfloat16(out[r]);
        *(bf16x8*)&x_out_b[(size_t)n * DIM + c0] = *(bf16x8*)tb;
    }
}

// ---------------- launch (7 dispatches) ----------------

extern "C" void kernel_launch(void* const* d_in, const int* in_sizes, int n_in,
                              void* d_out, int out_size, void* d_ws, size_t ws_size,
                              hipStream_t stream) {
    const float* x = (const float*)d_in[0];
    const int* ei = (const int*)d_in[1];
    const float* W1 = (const float*)d_in[2];
    const float* as1 = (const float*)d_in[3];
    const float* ad1 = (const float*)d_in[4];
    const float* b1 = (const float*)d_in[5];
    const float* g1 = (const float*)d_in[6];
    const float* be1 = (const float*)d_in[7];
    const float* W2 = (const float*)d_in[8];
    const float* as2 = (const float*)d_in[9];
    const float* ad2 = (const float*)d_in[10];
    const float* b2 = (const float*)d_in[11];
    const float* g2 = (const float*)d_in[12];
    const float* be2 = (const float*)d_in[13];
    float* out = (float*)d_out;

    char* ws = (char*)d_ws;
    size_t o = 0;
    auto alloc = [&](size_t bytes) { size_t r = o; o += (bytes + 255) & ~(size_t)255; return r; };
    int* p_cnt = (int*)(ws + alloc((size_t)NN * 4));
    int* p_off = (int*)(ws + alloc((size_t)(NN + 1) * 4));
    int* p_cur = (int*)(ws + alloc((size_t)NN * 4));
    int* p_slot = (int*)(ws + alloc((size_t)NE * 4));
    __hip_bfloat16* p_hb = (__hip_bfloat16*)(ws + alloc((size_t)NN * DIM * 2));
    __hip_bfloat16* p_xb = (__hip_bfloat16*)(ws + alloc((size_t)NN * DIM * 2));
    __hip_bfloat16* p_bt1 = (__hip_bfloat16*)(ws + alloc((size_t)DIM * DIM * 2));
    __hip_bfloat16* p_bt2 = (__hip_bfloat16*)(ws + alloc((size_t)DIM * DIM * 2));
    float* p_as = (float*)(ws + alloc((size_t)NN * 8 * 4));
    float* p_ad = (float*)(ws + alloc((size_t)NN * 8 * 4));
    float* p_as2 = (float*)(ws + alloc((size_t)NN * 4));
    float* p_ad2 = (float*)(ws + alloc((size_t)NN * 4));
    int* p_gtot = (int*)(ws + alloc(256));

    const int* e_src = ei;
    const int* e_dst = ei + NE;

    const int GB = 4 * ((NN + 127) / 128);   // 628 gemm blocks
    const int CB = (NE + 255) / 256;         // 1250 count/fill blocks

    // 1: conv x->bf16 + zero cnt/gtot + transpose W1,W2
    convz_k<<<NB_CONV + NB_ZERO + 512, 256, 0, stream>>>(x, p_xb, p_cnt, W1, W2, p_bt1, p_bt2,
                                                         p_gtot);
    // 2: layer-1 GEMM + fused edge-count tail
    gemm_mfma<8><<<GB + CB, 256, 0, stream>>>((const short*)p_xb, (const short*)p_bt1, p_hb,
                                              as1, ad1, p_as, p_ad, NN, e_dst, p_cnt, GB);
    // 3: parallel offset allocation (replaces single-block scan)
    alloc_k<<<(NN + 255) / 256, 256, 0, stream>>>(p_cnt, p_off, p_cur, p_gtot);
    // 4: CSR fill
    fill_k<<<CB, 256, 0, stream>>>(e_src, e_dst, p_cur, p_slot);
    // 5: layer-1 aggregation (+ zero p_as2/p_ad2 for gemm1's atomic epilogue)
    agg_k<8><<<NN / 4, 256, 0, stream>>>(p_hb, p_as, p_ad, p_off, p_cnt, p_slot, b1, g1, be1,
                                         p_xb, nullptr, p_xb, p_as2, p_ad2);
    // 6: layer-2 GEMM; alpha atomically accumulated into flat p_as2/p_ad2
    gemm_mfma<1><<<GB, 256, 0, stream>>>((const short*)p_xb, (const short*)p_bt2, p_hb,
                                         as2, ad2, p_as2, p_ad2, NN, nullptr, nullptr, GB);
    // 7: layer-2 aggregation -> final fp32 out
    agg_k<1><<<NN / 4, 256, 0, stream>>>(p_hb, p_as2, p_ad2, p_off, p_cnt, p_slot, b2, g2, be2,
                                         p_xb, out, nullptr, nullptr, nullptr);
}